// Round 10
// baseline (147.227 us; speedup 1.0000x reference)
//
#include <hip/hip_runtime.h>
#include <hip/hip_bf16.h>

#define BT 4
#define TT 4096
#define DM 1024
#define DH 64
#define NRE 17
#define LOG2E 1.4426950408889634f

using bf16 = __hip_bfloat16;
typedef __attribute__((ext_vector_type(8))) short short8;
typedef __attribute__((ext_vector_type(4))) short short4v;
typedef __attribute__((ext_vector_type(4))) float float4v;

#define BC8(x) __builtin_bit_cast(short8, x)

static __device__ __forceinline__ short8 load8(const bf16* p) {
    return *reinterpret_cast<const short8*>(p);
}
static __device__ __forceinline__ short bfbits(float x) {
    return (short)__bfloat16_as_ushort(__float2bfloat16(x));
}
static __device__ __forceinline__ short8 pack8(float4v a, float4v b) {
    short8 r;
    r[0] = bfbits(a[0]); r[1] = bfbits(a[1]); r[2] = bfbits(a[2]); r[3] = bfbits(a[3]);
    r[4] = bfbits(b[0]); r[5] = bfbits(b[1]); r[6] = bfbits(b[2]); r[7] = bfbits(b[3]);
    return r;
}
static __device__ __forceinline__ void gload_lds16(const void* g, void* l) {
    __builtin_amdgcn_global_load_lds(
        (const __attribute__((address_space(1))) void*)g,
        (__attribute__((address_space(3))) void*)l, 16, 0, 0);
}
static __device__ __forceinline__ unsigned lds_addr(const void* p) {
    return (unsigned)(size_t)(const __attribute__((address_space(3))) void*)p;
}

// invisible-to-waitcnt-pass LDS fragment read (offset must be a literal string)
#define DSR(dst, addr, off) \
    asm volatile("ds_read_b128 %0, %1 offset:" off : "=v"(dst) : "v"(addr))

// ===========================================================================
// Swizzled global layouts (16B units, frag-major) — identical to prior rounds.
// ===========================================================================

__global__ __launch_bounds__(256) void w_prep(
    const float* __restrict__ Wq, const float* __restrict__ Wk,
    const float* __restrict__ Wv, bf16* __restrict__ Wswz)
{
    const unsigned g = blockIdx.x * 256 + threadIdx.x;   // < 24576
    const unsigned c    = g / 768;
    const unsigned rem  = g - c * 768;
    const unsigned pair = rem >> 3;
    const unsigned slot = rem & 7;
    const unsigned l    = slot ^ (pair & 7);
    const unsigned row  = 2 * pair + (l >> 2);
    const unsigned k    = 32 * c + (l & 3) * 8;
    const float* src = (row < 64) ? &Wq[(size_t)row * DM + k]
                     : (row < 128) ? &Wk[(size_t)(row - 64) * DM + k]
                                   : &Wv[(size_t)(row - 128) * DM + k];
    float4v a = *reinterpret_cast<const float4v*>(src);
    float4v b = *reinterpret_cast<const float4v*>(src + 4);
    *reinterpret_cast<short8*>(&Wswz[(size_t)g * 8]) = pack8(a, b);
}

// ---------------------------------------------------------------------------
// Kernel 1: QKV GEMM. Unchanged (proven; not current bottleneck).
// ---------------------------------------------------------------------------
__global__ __launch_bounds__(256, 2) void qkv_gemm(
    const float* __restrict__ x, const bf16* __restrict__ Wswz,
    bf16* __restrict__ Qb, bf16* __restrict__ Kswz, bf16* __restrict__ Vswz)
{
    __shared__ __align__(16) float xs[2][2048];   // 2 x 8 KB  [row(32)][unit(16)]
    __shared__ __align__(16) short Wls[2][12288]; // 2 x 24 KB (2 swz chunks)

    const int w    = threadIdx.x >> 6;
    const int lane = threadIdx.x & 63;
    const int quad = lane >> 4;
    const int l16  = lane & 15;
    const int half = w & 1;
    const int colh = w >> 1;
    const int row0 = blockIdx.x * 32;

    float4v acc[6];
#pragma unroll
    for (int i = 0; i < 6; i++) acc[i] = (float4v)(0.f);

    auto stage = [&](int c, int p) {
#pragma unroll
        for (int j = 0; j < 2; j++) {
            const int call = 2 * w + j;
            const int row  = 4 * call + (lane >> 4);
            const int pu   = lane & 15;
            const int gu   = (pu & 8) | ((pu ^ row) & 7);
            gload_lds16(&x[(size_t)(row0 + row) * DM + c * 64 + gu * 4],
                        &xs[p][call * 256]);
        }
#pragma unroll
        for (int j = 0; j < 6; j++) {
            const int call = 6 * w + j;
            gload_lds16(&Wswz[(size_t)(2 * c) * 6144 + call * 512 + lane * 8],
                        &Wls[p][call * 512]);
        }
    };

    const unsigned xlds = lds_addr(&xs[0][0]);
    const unsigned wlds = lds_addr(&Wls[0][0]);
    const int R        = 16 * half + l16;
    const int lo3_0    = (2 * quad)     ^ (R & 7);
    const int lo3_1    = (2 * quad + 1) ^ (R & 7);
    const int pairBase = 48 * colh + (l16 >> 1);
    const int physW    = ((l16 & 1) * 4 + quad) ^ ((l16 >> 1) & 7);

    stage(0, 0);

    for (int c = 0; c < 16; c++) {
        const int p = c & 1;
        __syncthreads();
        if (c + 1 < 16) stage(c + 1, p ^ 1);

        const unsigned xb  = xlds + (unsigned)(p * 8192) + R * 64 * 4;
        const unsigned xa0 = xb + lo3_0 * 16;
        const unsigned xa1 = xb + lo3_1 * 16;
        const unsigned wa  = wlds + (unsigned)(p * 24576) + pairBase * 128 + physW * 16;

        float4v x00, x01, x10, x11;
        float4v w00, w01, w02, w03, w04, w05, w10, w11, w12, w13, w14, w15;
        DSR(x00, xa0, "0");   DSR(x10, xa0, "128");
        DSR(x01, xa1, "0");   DSR(x11, xa1, "128");
        DSR(w00, wa, "0");     DSR(w01, wa, "1024");  DSR(w02, wa, "2048");
        DSR(w03, wa, "3072");  DSR(w04, wa, "4096");  DSR(w05, wa, "5120");
        DSR(w10, wa, "12288"); DSR(w11, wa, "13312"); DSR(w12, wa, "14336");
        DSR(w13, wa, "15360"); DSR(w14, wa, "16384"); DSR(w15, wa, "17408");
        asm volatile("s_waitcnt lgkmcnt(0)"
            : "+v"(x00), "+v"(x01), "+v"(x10), "+v"(x11),
              "+v"(w00), "+v"(w01), "+v"(w02), "+v"(w03), "+v"(w04), "+v"(w05),
              "+v"(w10), "+v"(w11), "+v"(w12), "+v"(w13), "+v"(w14), "+v"(w15));

        short8 a0 = pack8(x00, x01);
        short8 a1 = pack8(x10, x11);
        acc[0] = __builtin_amdgcn_mfma_f32_16x16x32_bf16(a0, BC8(w00), acc[0], 0, 0, 0);
        acc[1] = __builtin_amdgcn_mfma_f32_16x16x32_bf16(a0, BC8(w01), acc[1], 0, 0, 0);
        acc[2] = __builtin_amdgcn_mfma_f32_16x16x32_bf16(a0, BC8(w02), acc[2], 0, 0, 0);
        acc[3] = __builtin_amdgcn_mfma_f32_16x16x32_bf16(a0, BC8(w03), acc[3], 0, 0, 0);
        acc[4] = __builtin_amdgcn_mfma_f32_16x16x32_bf16(a0, BC8(w04), acc[4], 0, 0, 0);
        acc[5] = __builtin_amdgcn_mfma_f32_16x16x32_bf16(a0, BC8(w05), acc[5], 0, 0, 0);
        acc[0] = __builtin_amdgcn_mfma_f32_16x16x32_bf16(a1, BC8(w10), acc[0], 0, 0, 0);
        acc[1] = __builtin_amdgcn_mfma_f32_16x16x32_bf16(a1, BC8(w11), acc[1], 0, 0, 0);
        acc[2] = __builtin_amdgcn_mfma_f32_16x16x32_bf16(a1, BC8(w12), acc[2], 0, 0, 0);
        acc[3] = __builtin_amdgcn_mfma_f32_16x16x32_bf16(a1, BC8(w13), acc[3], 0, 0, 0);
        acc[4] = __builtin_amdgcn_mfma_f32_16x16x32_bf16(a1, BC8(w14), acc[4], 0, 0, 0);
        acc[5] = __builtin_amdgcn_mfma_f32_16x16x32_bf16(a1, BC8(w15), acc[5], 0, 0, 0);
    }

    // ---- epilogue: Q direct; K/V through LDS images (alias xs) ----
    __syncthreads();
    short* Kimg = (short*)&xs[0][0];      // 4 KB (256 units)
    short* Vimg = Kimg + 2048;            // 4 KB
#pragma unroll
    for (int nt = 0; nt < 6; nt++) {
        const int cc = 96 * colh + 16 * nt + l16;          // 0..191
#pragma unroll
        for (int r = 0; r < 4; r++) {
            const int jl = 16 * half + 4 * quad + r;       // local row 0..31
            const short hb = bfbits(acc[nt][r]);
            if (cc < 64) {
                Qb[(size_t)(row0 + jl) * DH + cc] = __hip_bfloat16_raw{(unsigned short)hb};
            } else if (cc < 128) {
                const int k  = cc - 64;
                const int h  = k >> 5;
                const int q2 = (k & 31) >> 3;
                Kimg[((2 * half + h) * 64 + q2 * 16 + 4 * quad + r) * 8 + (k & 7)] = hb;
            } else {
                const int d  = cc - 128;
                const int dh = d >> 5;
                const int hi = (d >> 4) & 1;
                Vimg[((2 * half + dh) * 64 + quad * 16 + (d & 15)) * 8 + hi * 4 + r] = hb;
            }
        }
    }
    __syncthreads();
    {
        const int b_     = row0 >> 12;
        const int tile32 = (row0 & (TT - 1)) >> 5;
        const size_t base = ((size_t)(b_ * 512 + tile32 * 4)) * 512;  // elems
        const int u = threadIdx.x;                                    // 256 units
        *reinterpret_cast<short8*>(&Kswz[base + (size_t)u * 8]) =
            *reinterpret_cast<const short8*>(&Kimg[u * 8]);
        *reinterpret_cast<short8*>(&Vswz[base + (size_t)u * 8]) =
            *reinterpret_cast<const short8*>(&Vimg[u * 8]);
    }
}

// ---------------------------------------------------------------------------
// Kernel 2: flash causal attention — 12-wave pair blocks, register-direct KV,
// ones-MFMA l-sum + lazy max (R9 machinery unchanged).
// R9 ANALYSIS: attn ~36us vs ~10us of critical-path work at 2 waves/SIMD ->
// still stall-bound; 2-block co-residency never materializes. Allocator model
// from R2-R4 evidence: backend budgets VGPRs for 2 blocks/CU regardless of
// bounds (1024thr -> 8 waves/EU -> 64-reg cap, observed). By that model a
// 768-thr block budgets 6 waves/EU -> 85-reg cap, and R9's attn needs only
// 76 VGPRs -> fits. So: 256 blocks x 768 thr (12 waves) = 3 waves/SIMD in
// ONE block (+50% latency pool), and 12 KV streams cut the per-wave critical
// path from 17 to <=12 visits (-29%). Merge: 12 -> 4 (waves 4..11 retire to
// 8 LDS slots; waves 0..3 fold partners 4+w and 8+w in-register) -> 4-slot
// final. LDS 71KB (1 block/CU — all we ever get).
// ---------------------------------------------------------------------------
__global__ __launch_bounds__(768, 1) void attn(
    const bf16* __restrict__ Qb, const bf16* __restrict__ Kswz,
    const bf16* __restrict__ Vswz, const float* __restrict__ rel,
    float* __restrict__ out)
{
    __shared__ __align__(16) float smem[18176];  // 71 KB: Osh 8x32x68 + mM/lL 2x384

    const int w     = threadIdx.x >> 6;          // 0..11 (stream id)
    const int lane  = threadIdx.x & 63;
    const int quad  = lane >> 4;
    const int l16   = lane & 15;
    const int batch = blockIdx.x & 3;
    const int pr    = blockIdx.x >> 2;           // 0..63

    const float SCL = 0.125f * LOG2E;
    float relreg = 0.f;
    if (lane < NRE) relreg = rel[lane] * LOG2E;
    const float rel0 = __shfl(relreg, 0, 64);

    const size_t bbase = (size_t)batch * TT;

    float* Osh = smem;                           // 8 slots x [32 rows][68]
    float* mM  = Osh + 8 * 32 * 68;              // 384 (12 streams x 32 rows)
    float* lL  = mM + 384;

    const unsigned loff = (unsigned)lane * 8;    // elems within 512-elem unit row

    short4v ones4;                               // bf16 1.0 x4 (A-frag of ones-MFMA)
    ones4[0] = ones4[1] = ones4[2] = ones4[3] = (short)0x3F80;

#pragma unroll 1
    for (int ph = 0; ph < 2; ph++) {
        const int t  = ph ? (127 - pr) : pr;
        const int q0 = 32 * t;

        short8 bq[2][2];
#pragma unroll
        for (int qh = 0; qh < 2; qh++) {
            const bf16* qp = &Qb[(bbase + q0 + 16 * qh + l16) * DH];
            bq[qh][0] = load8(qp + quad * 8);
            bq[qh][1] = load8(qp + 32 + quad * 8);
        }

        float4v o[2][4];
        float4v o_l[2];                          // ones-MFMA l accumulator
#pragma unroll
        for (int qh = 0; qh < 2; qh++) {
            o_l[qh] = (float4v)(0.f);
#pragma unroll
            for (int dt = 0; dt < 4; dt++) o[qh][dt] = (float4v)(0.f);
        }
        float m_st[2] = {-1e30f, -1e30f};

        const int cnt = (t >= w) ? (((t - w) / 12) + 1) : 0;

        short8 K0, K1, K2, K3, V0, V1, V2, V3;
        if (cnt > 0) {
            const bf16* kp = Kswz + ((size_t)(batch * 512 + w * 4)) * 512 + loff;
            const bf16* vp = Vswz + ((size_t)(batch * 512 + w * 4)) * 512 + loff;
            K0 = load8(kp);        K1 = load8(kp + 512);
            K2 = load8(kp + 1024); K3 = load8(kp + 1536);
            V0 = load8(vp);        V1 = load8(vp + 512);
            V2 = load8(vp + 1024); V3 = load8(vp + 1536);
        }

        for (int k = 0; k < cnt; k++) {
            const int T  = w + 12 * k;
            const int js = 32 * T;
#pragma unroll
            for (int qh = 0; qh < 2; qh++) {
                float4v st[2];
                st[0] = (float4v)(0.f); st[1] = (float4v)(0.f);
                __builtin_amdgcn_s_setprio(1);
                st[0] = __builtin_amdgcn_mfma_f32_16x16x32_bf16(K0, bq[qh][0], st[0], 0, 0, 0);
                st[0] = __builtin_amdgcn_mfma_f32_16x16x32_bf16(K1, bq[qh][1], st[0], 0, 0, 0);
                st[1] = __builtin_amdgcn_mfma_f32_16x16x32_bf16(K2, bq[qh][0], st[1], 0, 0, 0);
                st[1] = __builtin_amdgcn_mfma_f32_16x16x32_bf16(K3, bq[qh][1], st[1], 0, 0, 0);
                __builtin_amdgcn_s_setprio(0);

                // K consumed for this tile after qh==1: prefetch next tile's K
                if (qh == 1 && k + 1 < cnt) {
                    const bf16* kp = Kswz + ((size_t)(batch * 512 + (T + 12) * 4)) * 512 + loff;
                    K0 = load8(kp);        K1 = load8(kp + 512);
                    K2 = load8(kp + 1024); K3 = load8(kp + 1536);
                }

                const int i_row = q0 + 16 * qh + l16;
                if (js + 40 <= q0 + 16 * qh) {       // interior: bias=rel0, no mask
#pragma unroll
                    for (int n = 0; n < 2; n++)
#pragma unroll
                        for (int r = 0; r < 4; r++)
                            st[n][r] = st[n][r] * SCL + rel0;
                } else {
#pragma unroll
                    for (int n = 0; n < 2; n++) {
                        const int jb = js + 16 * n + 4 * quad;
#pragma unroll
                        for (int r = 0; r < 4; r++) {
                            const int d = jb + r - i_row;
                            int idx = d + 8;
                            idx = idx < 0 ? 0 : (idx > 16 ? 16 : idx);
                            float v = st[n][r] * SCL + __shfl(relreg, idx, 64);
                            st[n][r] = (d > 0) ? -1e30f : v;
                        }
                    }
                }

                // in-lane max tree (no cross-lane in common path)
                const float m01 = fmaxf(fmaxf(st[0][0], st[0][1]), fmaxf(st[0][2], st[0][3]));
                const float m23 = fmaxf(fmaxf(st[1][0], st[1][1]), fmaxf(st[1][2], st[1][3]));
                const float mloc = fmaxf(m01, m23);

                // lazy defer-max: cross-lane reduce + rescale only on trigger
                if (__any(mloc > m_st[qh] + 8.f)) {
                    float mrow = fmaxf(mloc, __shfl_xor(mloc, 16, 64));
                    mrow = fmaxf(mrow, __shfl_xor(mrow, 32, 64));
                    const float mn = fmaxf(m_st[qh], mrow);
                    const float alpha = exp2f(m_st[qh] - mn);
                    m_st[qh] = mn;
#pragma unroll
                    for (int dt = 0; dt < 4; dt++)
#pragma unroll
                        for (int r = 0; r < 4; r++) o[qh][dt][r] *= alpha;
#pragma unroll
                    for (int r = 0; r < 4; r++) o_l[qh][r] *= alpha;
                }
                const float mn = m_st[qh];

                short4v pb[2];
#pragma unroll
                for (int n = 0; n < 2; n++)
#pragma unroll
                    for (int r = 0; r < 4; r++)
                        pb[n][r] = bfbits(exp2f(st[n][r] - mn));

                __builtin_amdgcn_s_setprio(1);
#pragma unroll
                for (int n = 0; n < 2; n++) {
                    // l row-sum via ones-MFMA (HW cross-quad contraction)
                    o_l[qh] = __builtin_amdgcn_mfma_f32_16x16x16bf16_1k(ones4, pb[n], o_l[qh], 0, 0, 0);
#pragma unroll
                    for (int dh = 0; dh < 2; dh++) {
                        const short8 vs = (dh == 0) ? ((n == 0) ? V0 : V2)
                                                    : ((n == 0) ? V1 : V3);
                        short4v lo, hi;
                        lo[0] = vs[0]; lo[1] = vs[1]; lo[2] = vs[2]; lo[3] = vs[3];
                        hi[0] = vs[4]; hi[1] = vs[5]; hi[2] = vs[6]; hi[3] = vs[7];
                        o[qh][2 * dh]     = __builtin_amdgcn_mfma_f32_16x16x16bf16_1k(lo, pb[n], o[qh][2 * dh], 0, 0, 0);
                        o[qh][2 * dh + 1] = __builtin_amdgcn_mfma_f32_16x16x16bf16_1k(hi, pb[n], o[qh][2 * dh + 1], 0, 0, 0);
                    }
                }
                __builtin_amdgcn_s_setprio(0);

                // V consumed for this tile after qh==1: prefetch next tile's V
                if (qh == 1 && k + 1 < cnt) {
                    const bf16* vp = Vswz + ((size_t)(batch * 512 + (T + 12) * 4)) * 512 + loff;
                    V0 = load8(vp);        V1 = load8(vp + 512);
                    V2 = load8(vp + 1024); V3 = load8(vp + 1536);
                }
            }
        }

        float l_st[2];
        l_st[0] = o_l[0][0];   // all 4 components equal (rows of ones-MFMA output)
        l_st[1] = o_l[1][0];

        // ---- hierarchical merge: 12 -> 4 -> 1 (all f32, no o-liveness stack) ----
        __syncthreads();                          // prior phase's merge reads done
        if (w >= 4) {                             // pass 1: waves 4..11 retire o NOW
            const int slot = w - 4;               // 0..7
#pragma unroll
            for (int qh = 0; qh < 2; qh++) {
                const int row = 16 * qh + l16;    // 0..31 within slot
                if (quad == 0) { mM[w * 32 + row] = m_st[qh]; lL[w * 32 + row] = l_st[qh]; }
#pragma unroll
                for (int dt = 0; dt < 4; dt++)
                    *reinterpret_cast<float4v*>(&Osh[(slot * 32 + row) * 68 + 16 * dt + 4 * quad]) = o[qh][dt];
            }
        }
        __syncthreads();
        if (w < 4) {                              // pass 2: fold streams 4+w, 8+w
#pragma unroll
            for (int qh = 0; qh < 2; qh++) {
                const int row = 16 * qh + l16;
                const float mp1 = mM[(4 + w) * 32 + row], lp1 = lL[(4 + w) * 32 + row];
                const float mp2 = mM[(8 + w) * 32 + row], lp2 = lL[(8 + w) * 32 + row];
                const float M  = fmaxf(fmaxf(m_st[qh], mp1), mp2);
                const float ea = exp2f(m_st[qh] - M);
                const float e1 = exp2f(mp1 - M);
                const float e2 = exp2f(mp2 - M);
                const float ln = l_st[qh] * ea + lp1 * e1 + lp2 * e2;
#pragma unroll
                for (int dt = 0; dt < 4; dt++) {
                    float4v op1 = *reinterpret_cast<float4v*>(&Osh[(w * 32 + row) * 68 + 16 * dt + 4 * quad]);       // slot w = stream 4+w
                    float4v op2 = *reinterpret_cast<float4v*>(&Osh[((w + 4) * 32 + row) * 68 + 16 * dt + 4 * quad]); // slot w+4 = stream 8+w
#pragma unroll
                    for (int r = 0; r < 4; r++)
                        o[qh][dt][r] = o[qh][dt][r] * ea + op1[r] * e1 + op2[r] * e2;
                }
                if (quad == 0) { mM[w * 32 + row] = M; lL[w * 32 + row] = ln; }
#pragma unroll
                for (int dt = 0; dt < 4; dt++)
                    *reinterpret_cast<float4v*>(&Osh[(w * 32 + row) * 68 + 16 * dt + 4 * quad]) = o[qh][dt];
            }
        }
        __syncthreads();
        {                                         // pass 3: 4-slot final merge
            for (int idx = threadIdx.x; idx < 32 * 64; idx += 768) {
                const int row = idx >> 6;
                const int col = idx & 63;
                float M = mM[row];
#pragma unroll
                for (int s = 1; s < 4; s++) M = fmaxf(M, mM[s * 32 + row]);
                float L = 0.f, a = 0.f;
#pragma unroll
                for (int s = 0; s < 4; s++) {
                    const float ex = exp2f(mM[s * 32 + row] - M);
                    L += lL[s * 32 + row] * ex;
                    a += Osh[(s * 32 + row) * 68 + col] * ex;
                }
                out[(bbase + q0 + row) * DH + col] = a / L;
            }
        }
        __syncthreads();   // merge reads done before next phase reuses smem
    }
}

// ---------------------------------------------------------------------------
extern "C" void kernel_launch(void* const* d_in, const int* in_sizes, int n_in,
                              void* d_out, int out_size, void* d_ws, size_t ws_size,
                              hipStream_t stream)
{
    const float* x   = (const float*)d_in[0];
    const float* Wq  = (const float*)d_in[1];
    const float* Wk  = (const float*)d_in[2];
    const float* Wv  = (const float*)d_in[3];
    const float* rel = (const float*)d_in[4];
    float* out = (float*)d_out;

    bf16* Qb   = (bf16*)d_ws;                         // [B*T,64]        2 MB
    bf16* Kswz = Qb   + (size_t)BT * TT * DH;         // frag-ordered    2 MB
    bf16* Vswz = Kswz + (size_t)BT * TT * DH;         // frag-ordered    2 MB
    bf16* Wswz = Vswz + (size_t)BT * TT * DH;         // swizzled W    384 KB

    w_prep<<<96, 256, 0, stream>>>(Wq, Wk, Wv, Wswz);
    qkv_gemm<<<512, 256, 0, stream>>>(x, Wswz, Qb, Kswz, Vswz);
    attn<<<256, 768, 0, stream>>>(Qb, Kswz, Vswz, rel, out);
}

// Round 11
// 139.234 us; speedup vs baseline: 1.0574x; 1.0574x over previous
//
#include <hip/hip_runtime.h>
#include <hip/hip_bf16.h>

#define BT 4
#define TT 4096
#define DM 1024
#define DH 64
#define NRE 17
#define LOG2E 1.4426950408889634f

using bf16 = __hip_bfloat16;
typedef __attribute__((ext_vector_type(8))) short short8;
typedef __attribute__((ext_vector_type(4))) short short4v;
typedef __attribute__((ext_vector_type(4))) float float4v;

#define BC8(x) __builtin_bit_cast(short8, x)

static __device__ __forceinline__ short8 load8(const bf16* p) {
    return *reinterpret_cast<const short8*>(p);
}
static __device__ __forceinline__ short bfbits(float x) {
    return (short)__bfloat16_as_ushort(__float2bfloat16(x));
}
static __device__ __forceinline__ short8 pack8(float4v a, float4v b) {
    short8 r;
    r[0] = bfbits(a[0]); r[1] = bfbits(a[1]); r[2] = bfbits(a[2]); r[3] = bfbits(a[3]);
    r[4] = bfbits(b[0]); r[5] = bfbits(b[1]); r[6] = bfbits(b[2]); r[7] = bfbits(b[3]);
    return r;
}
static __device__ __forceinline__ void gload_lds16(const void* g, void* l) {
    __builtin_amdgcn_global_load_lds(
        (const __attribute__((address_space(1))) void*)g,
        (__attribute__((address_space(3))) void*)l, 16, 0, 0);
}
static __device__ __forceinline__ unsigned lds_addr(const void* p) {
    return (unsigned)(size_t)(const __attribute__((address_space(3))) void*)p;
}

// invisible-to-waitcnt-pass LDS fragment read (offset must be a literal string)
#define DSR(dst, addr, off) \
    asm volatile("ds_read_b128 %0, %1 offset:" off : "=v"(dst) : "v"(addr))

// ===========================================================================
// Swizzled global layouts (16B units, frag-major) — identical to prior rounds.
// ===========================================================================

__global__ __launch_bounds__(256) void w_prep(
    const float* __restrict__ Wq, const float* __restrict__ Wk,
    const float* __restrict__ Wv, bf16* __restrict__ Wswz)
{
    const unsigned g = blockIdx.x * 256 + threadIdx.x;   // < 24576
    const unsigned c    = g / 768;
    const unsigned rem  = g - c * 768;
    const unsigned pair = rem >> 3;
    const unsigned slot = rem & 7;
    const unsigned l    = slot ^ (pair & 7);
    const unsigned row  = 2 * pair + (l >> 2);
    const unsigned k    = 32 * c + (l & 3) * 8;
    const float* src = (row < 64) ? &Wq[(size_t)row * DM + k]
                     : (row < 128) ? &Wk[(size_t)(row - 64) * DM + k]
                                   : &Wv[(size_t)(row - 128) * DM + k];
    float4v a = *reinterpret_cast<const float4v*>(src);
    float4v b = *reinterpret_cast<const float4v*>(src + 4);
    *reinterpret_cast<short8*>(&Wswz[(size_t)g * 8]) = pack8(a, b);
}

// ---------------------------------------------------------------------------
// Kernel 1: QKV GEMM — 64 rows/block, 512 thr (8 waves), grid 256.
// R10 ANALYSIS: qkv ~22us vs ~11us roofline; each of 512 blocks DMA'd the
// ENTIRE 384KB Wswz (192MB L2->LDS; 24 of 32 staging calls per chunk are W).
// THIS ROUND: double rows/block to 64 -> W DMA halves (96MB), staging calls
// per wave drop 8->5, and 8 waves/block = 2 waves/SIMD guaranteed within one
// block (no reliance on 2-block co-residency, which never materializes).
// Per-wave datapath byte-identical to the proven kernel (same fragments,
// same W LDS buffers); wave = row-group (w&3) x col-half (w>>2).
// LDS = 2x16KB x + 2x24KB W = 80KB. Epilogue: slab index rh>>1; K/V images
// 8KB each (alias xs); final copy = 512 units, contiguous across 2 slabs.
// ---------------------------------------------------------------------------
__global__ __launch_bounds__(512, 2) void qkv_gemm(
    const float* __restrict__ x, const bf16* __restrict__ Wswz,
    bf16* __restrict__ Qb, bf16* __restrict__ Kswz, bf16* __restrict__ Vswz)
{
    __shared__ __align__(16) float xs[2][4096];   // 2 x 16 KB [row(64)][unit(16)]
    __shared__ __align__(16) short Wls[2][12288]; // 2 x 24 KB (2 swz chunks)

    const int w    = threadIdx.x >> 6;   // 0..7
    const int lane = threadIdx.x & 63;
    const int quad = lane >> 4;
    const int l16  = lane & 15;
    const int rh   = w & 3;              // 16-row group 0..3
    const int colh = w >> 2;             // 96-col half 0..1
    const int row0 = blockIdx.x * 64;

    float4v acc[6];
#pragma unroll
    for (int i = 0; i < 6; i++) acc[i] = (float4v)(0.f);

    auto stage = [&](int c, int p) {
        // x: 16 calls (2/wave), 4 rows each, low-3-bit XOR unit swizzle
#pragma unroll
        for (int j = 0; j < 2; j++) {
            const int call = 2 * w + j;                  // 0..15
            const int row  = 4 * call + (lane >> 4);     // 0..63
            const int pu   = lane & 15;
            const int gu   = (pu & 8) | ((pu ^ row) & 7);
            gload_lds16(&x[(size_t)(row0 + row) * DM + c * 64 + gu * 4],
                        &xs[p][call * 256]);
        }
        // W: 24 calls (3/wave), identity copy of chunks 2c,2c+1
#pragma unroll
        for (int j = 0; j < 3; j++) {
            const int call = 3 * w + j;                  // 0..23
            gload_lds16(&Wswz[(size_t)(2 * c) * 6144 + call * 512 + lane * 8],
                        &Wls[p][call * 512]);
        }
    };

    const unsigned xlds = lds_addr(&xs[0][0]);
    const unsigned wlds = lds_addr(&Wls[0][0]);
    const int R        = 16 * rh + l16;                  // 0..63
    const int lo3_0    = (2 * quad)     ^ (R & 7);
    const int lo3_1    = (2 * quad + 1) ^ (R & 7);
    const int pairBase = 48 * colh + (l16 >> 1);
    const int physW    = ((l16 & 1) * 4 + quad) ^ ((l16 >> 1) & 7);

    stage(0, 0);

    for (int c = 0; c < 16; c++) {
        const int p = c & 1;
        __syncthreads();                      // drains stage(c) (pre-barrier vmcnt(0))
        if (c + 1 < 16) stage(c + 1, p ^ 1);

        const unsigned xb  = xlds + (unsigned)(p * 16384) + R * 64 * 4;
        const unsigned xa0 = xb + lo3_0 * 16;
        const unsigned xa1 = xb + lo3_1 * 16;
        const unsigned wa  = wlds + (unsigned)(p * 24576) + pairBase * 128 + physW * 16;

        float4v x00, x01, x10, x11;
        float4v w00, w01, w02, w03, w04, w05, w10, w11, w12, w13, w14, w15;
        DSR(x00, xa0, "0");   DSR(x10, xa0, "128");
        DSR(x01, xa1, "0");   DSR(x11, xa1, "128");
        DSR(w00, wa, "0");     DSR(w01, wa, "1024");  DSR(w02, wa, "2048");
        DSR(w03, wa, "3072");  DSR(w04, wa, "4096");  DSR(w05, wa, "5120");
        DSR(w10, wa, "12288"); DSR(w11, wa, "13312"); DSR(w12, wa, "14336");
        DSR(w13, wa, "15360"); DSR(w14, wa, "16384"); DSR(w15, wa, "17408");
        asm volatile("s_waitcnt lgkmcnt(0)"
            : "+v"(x00), "+v"(x01), "+v"(x10), "+v"(x11),
              "+v"(w00), "+v"(w01), "+v"(w02), "+v"(w03), "+v"(w04), "+v"(w05),
              "+v"(w10), "+v"(w11), "+v"(w12), "+v"(w13), "+v"(w14), "+v"(w15));

        short8 a0 = pack8(x00, x01);
        short8 a1 = pack8(x10, x11);
        acc[0] = __builtin_amdgcn_mfma_f32_16x16x32_bf16(a0, BC8(w00), acc[0], 0, 0, 0);
        acc[1] = __builtin_amdgcn_mfma_f32_16x16x32_bf16(a0, BC8(w01), acc[1], 0, 0, 0);
        acc[2] = __builtin_amdgcn_mfma_f32_16x16x32_bf16(a0, BC8(w02), acc[2], 0, 0, 0);
        acc[3] = __builtin_amdgcn_mfma_f32_16x16x32_bf16(a0, BC8(w03), acc[3], 0, 0, 0);
        acc[4] = __builtin_amdgcn_mfma_f32_16x16x32_bf16(a0, BC8(w04), acc[4], 0, 0, 0);
        acc[5] = __builtin_amdgcn_mfma_f32_16x16x32_bf16(a0, BC8(w05), acc[5], 0, 0, 0);
        acc[0] = __builtin_amdgcn_mfma_f32_16x16x32_bf16(a1, BC8(w10), acc[0], 0, 0, 0);
        acc[1] = __builtin_amdgcn_mfma_f32_16x16x32_bf16(a1, BC8(w11), acc[1], 0, 0, 0);
        acc[2] = __builtin_amdgcn_mfma_f32_16x16x32_bf16(a1, BC8(w12), acc[2], 0, 0, 0);
        acc[3] = __builtin_amdgcn_mfma_f32_16x16x32_bf16(a1, BC8(w13), acc[3], 0, 0, 0);
        acc[4] = __builtin_amdgcn_mfma_f32_16x16x32_bf16(a1, BC8(w14), acc[4], 0, 0, 0);
        acc[5] = __builtin_amdgcn_mfma_f32_16x16x32_bf16(a1, BC8(w15), acc[5], 0, 0, 0);
    }

    // ---- epilogue: Q direct; K/V through LDS images (alias xs) ----
    __syncthreads();
    short* Kimg = (short*)&xs[0][0];      // 8 KB (512 units, 2 slabs)
    short* Vimg = Kimg + 4096;            // 8 KB
#pragma unroll
    for (int nt = 0; nt < 6; nt++) {
        const int cc = 96 * colh + 16 * nt + l16;          // 0..191
#pragma unroll
        for (int r = 0; r < 4; r++) {
            const int jl   = 16 * rh + 4 * quad + r;       // local row 0..63
            const int slab = rh >> 1;                      // 32-row slab 0..1
            const int nt16 = rh & 1;                       // 16-row group in slab
            const short hb = bfbits(acc[nt][r]);
            if (cc < 64) {
                Qb[(size_t)(row0 + jl) * DH + cc] = __hip_bfloat16_raw{(unsigned short)hb};
            } else if (cc < 128) {
                const int k  = cc - 64;
                const int h  = k >> 5;
                const int q2 = (k & 31) >> 3;
                Kimg[slab * 2048 +
                     ((2 * nt16 + h) * 64 + q2 * 16 + 4 * quad + r) * 8 + (k & 7)] = hb;
            } else {
                const int d  = cc - 128;
                const int dh = d >> 5;
                const int hi = (d >> 4) & 1;
                Vimg[slab * 2048 +
                     ((2 * nt16 + dh) * 64 + quad * 16 + (d & 15)) * 8 + hi * 4 + r] = hb;
            }
        }
    }
    __syncthreads();
    {
        const int b_     = row0 >> 12;
        const int tile32 = (row0 & (TT - 1)) >> 5;
        const size_t base = ((size_t)(b_ * 512 + tile32 * 4)) * 512;  // elems
        const int u = threadIdx.x;                                    // 512 units (2 slabs)
        *reinterpret_cast<short8*>(&Kswz[base + (size_t)u * 8]) =
            *reinterpret_cast<const short8*>(&Kimg[u * 8]);
        *reinterpret_cast<short8*>(&Vswz[base + (size_t)u * 8]) =
            *reinterpret_cast<const short8*>(&Vimg[u * 8]);
    }
}

// ---------------------------------------------------------------------------
// Kernel 2: flash causal attention — pair blocks, register-direct KV,
// ones-MFMA l-sum + lazy max. EXACT R9 version (session-best 144.3us total;
// R10's 12-wave variant was +3us and is reverted).
// 256 blocks (4 batch x 64 pairs) x 512 thr; 8 KV streams (T ≡ w mod 8),
// 17 visits/wave for every pr (129 = 8*16+1) -> exact balance.
// ---------------------------------------------------------------------------
__global__ __launch_bounds__(512, 2) void attn(
    const bf16* __restrict__ Qb, const bf16* __restrict__ Kswz,
    const bf16* __restrict__ Vswz, const float* __restrict__ rel,
    float* __restrict__ out)
{
    __shared__ __align__(16) float smem[9216];   // 36 KB: Osh 4x32x68 + mM/lL

    const int w     = threadIdx.x >> 6;          // 0..7
    const int lane  = threadIdx.x & 63;
    const int quad  = lane >> 4;
    const int l16   = lane & 15;
    const int batch = blockIdx.x & 3;
    const int pr    = blockIdx.x >> 2;           // 0..63

    const float SCL = 0.125f * LOG2E;
    float relreg = 0.f;
    if (lane < NRE) relreg = rel[lane] * LOG2E;
    const float rel0 = __shfl(relreg, 0, 64);

    const size_t bbase = (size_t)batch * TT;

    float* Osh = smem;                           // 4 slots x [32 rows][68]
    float* mM  = Osh + 4 * 32 * 68;              // 256 (8 streams x 32 rows)
    float* lL  = mM + 256;

    const unsigned loff = (unsigned)lane * 8;    // elems within 512-elem unit row

    short4v ones4;                               // bf16 1.0 x4 (A-frag of ones-MFMA)
    ones4[0] = ones4[1] = ones4[2] = ones4[3] = (short)0x3F80;

#pragma unroll 1
    for (int ph = 0; ph < 2; ph++) {
        const int t  = ph ? (127 - pr) : pr;
        const int q0 = 32 * t;

        short8 bq[2][2];
#pragma unroll
        for (int qh = 0; qh < 2; qh++) {
            const bf16* qp = &Qb[(bbase + q0 + 16 * qh + l16) * DH];
            bq[qh][0] = load8(qp + quad * 8);
            bq[qh][1] = load8(qp + 32 + quad * 8);
        }

        float4v o[2][4];
        float4v o_l[2];                          // ones-MFMA l accumulator
#pragma unroll
        for (int qh = 0; qh < 2; qh++) {
            o_l[qh] = (float4v)(0.f);
#pragma unroll
            for (int dt = 0; dt < 4; dt++) o[qh][dt] = (float4v)(0.f);
        }
        float m_st[2] = {-1e30f, -1e30f};

        const int cnt = (t >= w) ? (((t - w) >> 3) + 1) : 0;

        short8 K0, K1, K2, K3, V0, V1, V2, V3;
        if (cnt > 0) {
            const bf16* kp = Kswz + ((size_t)(batch * 512 + w * 4)) * 512 + loff;
            const bf16* vp = Vswz + ((size_t)(batch * 512 + w * 4)) * 512 + loff;
            K0 = load8(kp);        K1 = load8(kp + 512);
            K2 = load8(kp + 1024); K3 = load8(kp + 1536);
            V0 = load8(vp);        V1 = load8(vp + 512);
            V2 = load8(vp + 1024); V3 = load8(vp + 1536);
        }

        for (int k = 0; k < cnt; k++) {
            const int T  = w + 8 * k;
            const int js = 32 * T;
#pragma unroll
            for (int qh = 0; qh < 2; qh++) {
                float4v st[2];
                st[0] = (float4v)(0.f); st[1] = (float4v)(0.f);
                __builtin_amdgcn_s_setprio(1);
                st[0] = __builtin_amdgcn_mfma_f32_16x16x32_bf16(K0, bq[qh][0], st[0], 0, 0, 0);
                st[0] = __builtin_amdgcn_mfma_f32_16x16x32_bf16(K1, bq[qh][1], st[0], 0, 0, 0);
                st[1] = __builtin_amdgcn_mfma_f32_16x16x32_bf16(K2, bq[qh][0], st[1], 0, 0, 0);
                st[1] = __builtin_amdgcn_mfma_f32_16x16x32_bf16(K3, bq[qh][1], st[1], 0, 0, 0);
                __builtin_amdgcn_s_setprio(0);

                // K consumed for this tile after qh==1: prefetch next tile's K
                if (qh == 1 && k + 1 < cnt) {
                    const bf16* kp = Kswz + ((size_t)(batch * 512 + (T + 8) * 4)) * 512 + loff;
                    K0 = load8(kp);        K1 = load8(kp + 512);
                    K2 = load8(kp + 1024); K3 = load8(kp + 1536);
                }

                const int i_row = q0 + 16 * qh + l16;
                if (js + 40 <= q0 + 16 * qh) {       // interior: bias=rel0, no mask
#pragma unroll
                    for (int n = 0; n < 2; n++)
#pragma unroll
                        for (int r = 0; r < 4; r++)
                            st[n][r] = st[n][r] * SCL + rel0;
                } else {
#pragma unroll
                    for (int n = 0; n < 2; n++) {
                        const int jb = js + 16 * n + 4 * quad;
#pragma unroll
                        for (int r = 0; r < 4; r++) {
                            const int d = jb + r - i_row;
                            int idx = d + 8;
                            idx = idx < 0 ? 0 : (idx > 16 ? 16 : idx);
                            float v = st[n][r] * SCL + __shfl(relreg, idx, 64);
                            st[n][r] = (d > 0) ? -1e30f : v;
                        }
                    }
                }

                // in-lane max tree (no cross-lane in common path)
                const float m01 = fmaxf(fmaxf(st[0][0], st[0][1]), fmaxf(st[0][2], st[0][3]));
                const float m23 = fmaxf(fmaxf(st[1][0], st[1][1]), fmaxf(st[1][2], st[1][3]));
                const float mloc = fmaxf(m01, m23);

                // lazy defer-max: cross-lane reduce + rescale only on trigger
                if (__any(mloc > m_st[qh] + 8.f)) {
                    float mrow = fmaxf(mloc, __shfl_xor(mloc, 16, 64));
                    mrow = fmaxf(mrow, __shfl_xor(mrow, 32, 64));
                    const float mn = fmaxf(m_st[qh], mrow);
                    const float alpha = exp2f(m_st[qh] - mn);
                    m_st[qh] = mn;
#pragma unroll
                    for (int dt = 0; dt < 4; dt++)
#pragma unroll
                        for (int r = 0; r < 4; r++) o[qh][dt][r] *= alpha;
#pragma unroll
                    for (int r = 0; r < 4; r++) o_l[qh][r] *= alpha;
                }
                const float mn = m_st[qh];

                short4v pb[2];
#pragma unroll
                for (int n = 0; n < 2; n++)
#pragma unroll
                    for (int r = 0; r < 4; r++)
                        pb[n][r] = bfbits(exp2f(st[n][r] - mn));

                __builtin_amdgcn_s_setprio(1);
#pragma unroll
                for (int n = 0; n < 2; n++) {
                    // l row-sum via ones-MFMA (HW cross-quad contraction)
                    o_l[qh] = __builtin_amdgcn_mfma_f32_16x16x16bf16_1k(ones4, pb[n], o_l[qh], 0, 0, 0);
#pragma unroll
                    for (int dh = 0; dh < 2; dh++) {
                        const short8 vs = (dh == 0) ? ((n == 0) ? V0 : V2)
                                                    : ((n == 0) ? V1 : V3);
                        short4v lo, hi;
                        lo[0] = vs[0]; lo[1] = vs[1]; lo[2] = vs[2]; lo[3] = vs[3];
                        hi[0] = vs[4]; hi[1] = vs[5]; hi[2] = vs[6]; hi[3] = vs[7];
                        o[qh][2 * dh]     = __builtin_amdgcn_mfma_f32_16x16x16bf16_1k(lo, pb[n], o[qh][2 * dh], 0, 0, 0);
                        o[qh][2 * dh + 1] = __builtin_amdgcn_mfma_f32_16x16x16bf16_1k(hi, pb[n], o[qh][2 * dh + 1], 0, 0, 0);
                    }
                }
                __builtin_amdgcn_s_setprio(0);

                // V consumed for this tile after qh==1: prefetch next tile's V
                if (qh == 1 && k + 1 < cnt) {
                    const bf16* vp = Vswz + ((size_t)(batch * 512 + (T + 8) * 4)) * 512 + loff;
                    V0 = load8(vp);        V1 = load8(vp + 512);
                    V2 = load8(vp + 1024); V3 = load8(vp + 1536);
                }
            }
        }

        float l_st[2];
        l_st[0] = o_l[0][0];   // all 4 components equal (rows of ones-MFMA output)
        l_st[1] = o_l[1][0];

        // ---- hierarchical merge: 8 -> 4 -> 1 (all f32, no o-liveness stack) ----
        __syncthreads();                          // prior phase's merge reads done
        if (w >= 4) {                             // pass 1: high waves retire o NOW
            const int slot = w - 4;
#pragma unroll
            for (int qh = 0; qh < 2; qh++) {
                const int row = 16 * qh + l16;    // 0..31 within slot
                if (quad == 0) { mM[w * 32 + row] = m_st[qh]; lL[w * 32 + row] = l_st[qh]; }
#pragma unroll
                for (int dt = 0; dt < 4; dt++)
                    *reinterpret_cast<float4v*>(&Osh[(slot * 32 + row) * 68 + 16 * dt + 4 * quad]) = o[qh][dt];
            }
        }
        __syncthreads();
        if (w < 4) {                              // pass 2: fold partner into regs
#pragma unroll
            for (int qh = 0; qh < 2; qh++) {
                const int row = 16 * qh + l16;
                const float mp = mM[(w + 4) * 32 + row], lp = lL[(w + 4) * 32 + row];
                const float M  = fmaxf(m_st[qh], mp);
                const float ea = exp2f(m_st[qh] - M);
                const float eb = exp2f(mp - M);
                const float ln = l_st[qh] * ea + lp * eb;
#pragma unroll
                for (int dt = 0; dt < 4; dt++) {
                    float4v op = *reinterpret_cast<float4v*>(&Osh[(w * 32 + row) * 68 + 16 * dt + 4 * quad]);
#pragma unroll
                    for (int r = 0; r < 4; r++) o[qh][dt][r] = o[qh][dt][r] * ea + op[r] * eb;
                }
                if (quad == 0) { mM[w * 32 + row] = M; lL[w * 32 + row] = ln; }
#pragma unroll
                for (int dt = 0; dt < 4; dt++)
                    *reinterpret_cast<float4v*>(&Osh[(w * 32 + row) * 68 + 16 * dt + 4 * quad]) = o[qh][dt];
            }
        }
        __syncthreads();
        {                                         // pass 3: 4-slot final merge
            for (int idx = threadIdx.x; idx < 32 * 64; idx += 512) {
                const int row = idx >> 6;
                const int col = idx & 63;
                float M = mM[row];
#pragma unroll
                for (int s = 1; s < 4; s++) M = fmaxf(M, mM[s * 32 + row]);
                float L = 0.f, a = 0.f;
#pragma unroll
                for (int s = 0; s < 4; s++) {
                    const float ex = exp2f(mM[s * 32 + row] - M);
                    L += lL[s * 32 + row] * ex;
                    a += Osh[(s * 32 + row) * 68 + col] * ex;
                }
                out[(bbase + q0 + row) * DH + col] = a / L;
            }
        }
        __syncthreads();   // merge reads done before next phase reuses smem
    }
}

// ---------------------------------------------------------------------------
extern "C" void kernel_launch(void* const* d_in, const int* in_sizes, int n_in,
                              void* d_out, int out_size, void* d_ws, size_t ws_size,
                              hipStream_t stream)
{
    const float* x   = (const float*)d_in[0];
    const float* Wq  = (const float*)d_in[1];
    const float* Wk  = (const float*)d_in[2];
    const float* Wv  = (const float*)d_in[3];
    const float* rel = (const float*)d_in[4];
    float* out = (float*)d_out;

    bf16* Qb   = (bf16*)d_ws;                         // [B*T,64]        2 MB
    bf16* Kswz = Qb   + (size_t)BT * TT * DH;         // frag-ordered    2 MB
    bf16* Vswz = Kswz + (size_t)BT * TT * DH;         // frag-ordered    2 MB
    bf16* Wswz = Vswz + (size_t)BT * TT * DH;         // swizzled W    384 KB

    w_prep<<<96, 256, 0, stream>>>(Wq, Wk, Wv, Wswz);
    qkv_gemm<<<256, 512, 0, stream>>>(x, Wswz, Qb, Kswz, Vswz);
    attn<<<256, 512, 0, stream>>>(Qb, Kswz, Vswz, rel, out);
}